// Round 2
// baseline (124.902 us; speedup 1.0000x reference)
//
#include <hip/hip_runtime.h>
#include <math.h>

#define B_  32
#define T_  4096
#define TP_ 1024
#define J_  55
#define D_  6
#define CH_ 330     // J_*D_
#define Z_  128
#define L_  128     // chunk length
#define W_  128     // warmup steps (0.95^128 ~ 1.4e-3 decay)
#define C_  32      // T_/L_

__constant__ float c_mass[55] = {
  0.1117f, 0.1416f, 0.1416f, 0.1633f, 0.0433f, 0.0433f, 0.1596f, 0.0137f,
  0.0137f, 0.1596f, 0.0137f, 0.0137f, 0.035f,  0.008f,  0.008f,  0.0694f,
  0.0271f, 0.0271f, 0.0162f, 0.0162f, 0.0061f, 0.0061f, 0.007f,  0.001f,
  0.001f,
  0.0004f,0.0004f,0.0004f,0.0004f,0.0004f,0.0004f,0.0004f,0.0004f,0.0004f,0.0004f,
  0.0004f,0.0004f,0.0004f,0.0004f,0.0004f,0.0004f,0.0004f,0.0004f,0.0004f,0.0004f,
  0.0004f,0.0004f,0.0004f,0.0004f,0.0004f,0.0004f,0.0004f,0.0004f,0.0004f,0.0004f
};

// scale[b,tp] = 0.5*(1-psi)*(1+mean(exp(logvar))) ; one wave per row
__global__ __launch_bounds__(256) void scale_kernel(const float* __restrict__ psi,
                                                    const float* __restrict__ logvar,
                                                    float* __restrict__ scale) {
  int row  = blockIdx.x * 4 + (threadIdx.x >> 6);   // 4 waves/block, 1 row/wave
  int lane = threadIdx.x & 63;
  float2 v = reinterpret_cast<const float2*>(logvar + (size_t)row * Z_)[lane];
  float e = __expf(v.x) + __expf(v.y);
  #pragma unroll
  for (int off = 32; off > 0; off >>= 1) e += __shfl_down(e, off, 64);
  if (lane == 0) {
    float sigma = e * (1.0f / 128.0f);
    scale[row] = 0.5f * (1.0f - psi[row]) * (1.0f + sigma);
  }
}

// One block per (chunk, batch). Thread = one of 330 (j,d) channels.
__global__ __launch_bounds__(384) void smooth_kernel(const float* __restrict__ x,
                                                     const float* __restrict__ scale,
                                                     const float* __restrict__ init,
                                                     float* __restrict__ out) {
  const int c   = blockIdx.x;
  const int b   = blockIdx.y;
  const int tid = threadIdx.x;

  __shared__ float s_scale[(L_ + W_) / 4];

  const int t0  = c * L_;
  const int tw  = (c == 0) ? 0 : (t0 - W_);
  const int tpw = tw >> 2;
  const int nsc = (t0 + L_ - tw) >> 2;
  for (int i = tid; i < nsc; i += 384) s_scale[i] = scale[b * TP_ + tpw + i];
  __syncthreads();
  if (tid >= CH_) return;

  const int j = tid / 6;
  const float shape = fmaxf(sqrtf(c_mass[j] * (1.0f / 0.1633f)), 0.1f);

  float state = (c == 0) ? init[b * CH_ + tid] : 0.0f;
  const float* xp = x + ((size_t)b * T_ + tw) * CH_ + tid;
  float*       op = out + ((size_t)b * T_ + t0) * CH_ + tid;

  int gbase = 0;
  if (c != 0) {
    // warmup: converge state, no stores (reads hit L3 — poses fits in 256MB)
    #pragma unroll 4
    for (int g = 0; g < W_ / 4; ++g) {
      float tau = fminf(fmaxf(s_scale[g] * shape, 0.0f), 0.95f);
      #pragma unroll
      for (int k = 0; k < 4; ++k) {
        float xv = xp[(g * 4 + k) * CH_];
        state = fmaf(tau, state - xv, xv);   // (1-tau)*x + tau*state
      }
    }
    xp += W_ * CH_;
    gbase = W_ / 4;
  }

  // main: compute and store the chunk
  #pragma unroll 4
  for (int g = 0; g < L_ / 4; ++g) {
    float tau = fminf(fmaxf(s_scale[gbase + g] * shape, 0.0f), 0.95f);
    #pragma unroll
    for (int k = 0; k < 4; ++k) {
      float xv = xp[(g * 4 + k) * CH_];
      state = fmaf(tau, state - xv, xv);
      op[(g * 4 + k) * CH_] = state;
    }
  }
}

extern "C" void kernel_launch(void* const* d_in, const int* in_sizes, int n_in,
                              void* d_out, int out_size, void* d_ws, size_t ws_size,
                              hipStream_t stream) {
  const float* poses  = (const float*)d_in[0];  // (32,4096,55,6)
  const float* psi    = (const float*)d_in[1];  // (32,1024)
  const float* logvar = (const float*)d_in[2];  // (32,1024,128)
  const float* init   = (const float*)d_in[3];  // (32,55,6)
  float* out   = (float*)d_out;                 // (32,4096,55,6)
  float* scale = (float*)d_ws;                  // 32*1024 floats = 128 KB

  scale_kernel<<<dim3(B_ * TP_ / 4), 256, 0, stream>>>(psi, logvar, scale);
  smooth_kernel<<<dim3(C_, B_), 384, 0, stream>>>(poses, scale, init, out);
}

// Round 4
// 94.523 us; speedup vs baseline: 1.3214x; 1.3214x over previous
//
#include <hip/hip_runtime.h>
#include <math.h>

#define B_   32
#define T_   4096
#define TP_  1024
#define CH_  330
#define CH2_ 165    // float2 channels per frame
#define Z_   128
#define L_   128    // chunk length
#define W_   128    // warmup steps (0.95^128 ~ 1.4e-3 decay; measured absmax 0.0156 << 0.108)
#define C_   32     // T_/L_
#define G_   16     // register pipeline group (16 float2 loads in flight)

typedef float f2 __attribute__((ext_vector_type(2)));

__constant__ float c_mass[55] = {
  0.1117f, 0.1416f, 0.1416f, 0.1633f, 0.0433f, 0.0433f, 0.1596f, 0.0137f,
  0.0137f, 0.1596f, 0.0137f, 0.0137f, 0.035f,  0.008f,  0.008f,  0.0694f,
  0.0271f, 0.0271f, 0.0162f, 0.0162f, 0.0061f, 0.0061f, 0.007f,  0.001f,
  0.001f,
  0.0004f,0.0004f,0.0004f,0.0004f,0.0004f,0.0004f,0.0004f,0.0004f,0.0004f,0.0004f,
  0.0004f,0.0004f,0.0004f,0.0004f,0.0004f,0.0004f,0.0004f,0.0004f,0.0004f,0.0004f,
  0.0004f,0.0004f,0.0004f,0.0004f,0.0004f,0.0004f,0.0004f,0.0004f,0.0004f,0.0004f
};

// scale[b,tp] = 0.5*(1-psi)*(1+mean(exp(logvar))) ; one wave per row
__global__ __launch_bounds__(256) void scale_kernel(const float* __restrict__ psi,
                                                    const float* __restrict__ logvar,
                                                    float* __restrict__ scale) {
  int row  = blockIdx.x * 4 + (threadIdx.x >> 6);   // 4 waves/block, 1 row/wave
  int lane = threadIdx.x & 63;
  f2 v = reinterpret_cast<const f2*>(logvar + (size_t)row * Z_)[lane];
  float e = __expf(v.x) + __expf(v.y);
  #pragma unroll
  for (int off = 32; off > 0; off >>= 1) e += __shfl_down(e, off, 64);
  if (lane == 0) {
    scale[row] = 0.5f * (1.0f - psi[row]) * (1.0f + e * (1.0f / 128.0f));
  }
}

// One block per (chunk, batch). Thread = one float2 (2 adjacent channels, same joint).
__global__ __launch_bounds__(192) void smooth_kernel(const float* __restrict__ x,
                                                     const float* __restrict__ scale,
                                                     const float* __restrict__ init,
                                                     float* __restrict__ out) {
  const int c   = blockIdx.x;
  const int b   = blockIdx.y;
  const int tid = threadIdx.x;

  __shared__ float s_scale[(L_ + W_) / 4];

  const int t0     = c * L_;
  const int tw     = (c == 0) ? 0 : (t0 - W_);
  const int nsteps = t0 + L_ - tw;            // 128 (c==0) or 256
  const int nsc    = nsteps >> 2;
  for (int i = tid; i < nsc; i += 192) s_scale[i] = scale[b * TP_ + (tw >> 2) + i];
  __syncthreads();
  if (tid >= CH2_) return;

  // channels (2*tid, 2*tid+1) share joint tid/3 (6 floats/joint, 6 even)
  const float shape = fmaxf(sqrtf(c_mass[tid / 3] * (1.0f / 0.1633f)), 0.1f);

  f2 st;
  if (c == 0) st = reinterpret_cast<const f2*>(init)[(size_t)b * CH2_ + tid];
  else        st = (f2)(0.0f);

  const f2* xp = reinterpret_cast<const f2*>(x) + ((size_t)b * T_ + tw) * CH2_ + tid;
  f2*       op = reinterpret_cast<f2*>(out)     + ((size_t)b * T_ + t0) * CH2_ + tid;

  f2 bufA[G_], bufB[G_];

  auto loadG = [&](f2* buf) {
    #pragma unroll
    for (int k = 0; k < G_; ++k) buf[k] = xp[k * CH2_];
    xp += G_ * CH2_;
  };
  // gt: group index into s_scale (4 entries per group of 16 steps)
  auto compG = [&](const f2* buf, int gt, bool emit) {
    float ta[4];
    #pragma unroll
    for (int q = 0; q < 4; ++q)
      ta[q] = fminf(fmaxf(s_scale[gt * 4 + q] * shape, 0.0f), 0.95f);
    #pragma unroll
    for (int k = 0; k < G_; ++k) {
      float tq = ta[k >> 2];
      st.x = fmaf(tq, st.x - buf[k].x, buf[k].x);   // (1-tau)*x + tau*state
      st.y = fmaf(tq, st.y - buf[k].y, buf[k].y);
      if (emit) __builtin_nontemporal_store(st, &op[k * CH2_]);
    }
    if (emit) op += G_ * CH2_;
  };

  if (c != 0) {
    // warmup: converge state, no stores; ping-pong keeps 16-32 loads in flight
    loadG(bufA);
    #pragma unroll
    for (int g = 0; g < W_ / G_; g += 2) {
      loadG(bufB);
      compG(bufA, g, false);
      if (g + 2 < W_ / G_) loadG(bufA);
      compG(bufB, g + 1, false);
    }
  }

  const int gBase = (nsteps - L_) / G_;   // 8 (c>0) or 0
  loadG(bufA);
  #pragma unroll
  for (int g = 0; g < L_ / G_; g += 2) {
    loadG(bufB);
    compG(bufA, gBase + g, true);
    if (g + 2 < L_ / G_) loadG(bufA);
    compG(bufB, gBase + g + 1, true);
  }
}

extern "C" void kernel_launch(void* const* d_in, const int* in_sizes, int n_in,
                              void* d_out, int out_size, void* d_ws, size_t ws_size,
                              hipStream_t stream) {
  const float* poses  = (const float*)d_in[0];  // (32,4096,55,6)
  const float* psi    = (const float*)d_in[1];  // (32,1024)
  const float* logvar = (const float*)d_in[2];  // (32,1024,128)
  const float* init   = (const float*)d_in[3];  // (32,55,6)
  float* out   = (float*)d_out;                 // (32,4096,55,6)
  float* scale = (float*)d_ws;                  // 32*1024 floats = 128 KB

  scale_kernel<<<dim3(B_ * TP_ / 4), 256, 0, stream>>>(psi, logvar, scale);
  smooth_kernel<<<dim3(C_, B_), 192, 0, stream>>>(poses, scale, init, out);
}